// Round 1
// baseline (104.045 us; speedup 1.0000x reference)
//
#include <hip/hip_runtime.h>
#include <math.h>

#define TOKENS 16384
#define HIDDEN 2048
#define NEXP   64
#define MBLK   64
#define KBLK   16
#define NWAVE  4
#define KCH    (HIDDEN / NWAVE)   // 512 per wave
#define NTILE  (KCH / KBLK)       // 32
#define TOPK   6
#define NGROUP 8
#define TOPKG  3

__global__ __launch_bounds__(256, 1)
void moe_gate_kernel(const float* __restrict__ X, const float* __restrict__ W,
                     float* __restrict__ out, int half_out)
{
    // per-wave private staging tiles (pad +1 float: all accesses <=2-way conflict)
    __shared__ float xs[NWAVE][MBLK][KBLK + 1];   // 4*64*17*4 = 17408 B
    __shared__ float wl[NWAVE][NEXP][KBLK + 1];   // 17408 B
    __shared__ float red[MBLK][NEXP + 1];         // 16640 B   (total 51456 B)

    const int tid  = threadIdx.x;
    const int wv   = tid >> 6;        // wave 0..3 owns K chunk
    const int lane = tid & 63;
    const int lr   = lane >> 3;       // 0..7
    const int lc   = lane & 7;        // 0..7
    const int row0 = blockIdx.x * MBLK;
    const int kb0  = wv * KCH;

    // staging lane assignment: 4 lanes per row, float4 each
    const int sr = lane >> 2;         // 0..15
    const int sc = lane & 3;          // 0..3

    float acc[8][8];
#pragma unroll
    for (int i = 0; i < 8; ++i)
#pragma unroll
        for (int j = 0; j < 8; ++j) acc[i][j] = 0.f;

    const float* xb = X + (size_t)row0 * HIDDEN + kb0;
    const float* wb = W + kb0;

    float4 px[4], pw[4];

    // ---- prologue: load tile 0 into registers
#pragma unroll
    for (int it = 0; it < 4; ++it) {
        int r = it * 16 + sr;
        px[it] = *(const float4*)(xb + (size_t)r * HIDDEN + sc * 4);
        pw[it] = *(const float4*)(wb + (size_t)r * HIDDEN + sc * 4);
    }

    for (int t = 0; t < NTILE; ++t) {
        // store prefetched tile to LDS
#pragma unroll
        for (int it = 0; it < 4; ++it) {
            int r = it * 16 + sr;
            float* dx = &xs[wv][r][sc * 4];
            dx[0] = px[it].x; dx[1] = px[it].y; dx[2] = px[it].z; dx[3] = px[it].w;
            float* dw = &wl[wv][r][sc * 4];
            dw[0] = pw[it].x; dw[1] = pw[it].y; dw[2] = pw[it].z; dw[3] = pw[it].w;
        }
        __syncthreads();

        // prefetch tile t+1 (overlaps with compute below)
        if (t + 1 < NTILE) {
            const float* xt = xb + (t + 1) * KBLK;
            const float* wt = wb + (t + 1) * KBLK;
#pragma unroll
            for (int it = 0; it < 4; ++it) {
                int r = it * 16 + sr;
                px[it] = *(const float4*)(xt + (size_t)r * HIDDEN + sc * 4);
                pw[it] = *(const float4*)(wt + (size_t)r * HIDDEN + sc * 4);
            }
        }

        // compute: 16 k-steps x 64 FMA per lane
#pragma unroll 4
        for (int kk = 0; kk < KBLK; ++kk) {
            float a[8], b[8];
#pragma unroll
            for (int i = 0; i < 8; ++i) a[i] = xs[wv][i * 8 + lr][kk];
#pragma unroll
            for (int j = 0; j < 8; ++j) b[j] = wl[wv][j * 8 + lc][kk];
#pragma unroll
            for (int i = 0; i < 8; ++i)
#pragma unroll
                for (int j = 0; j < 8; ++j)
                    acc[i][j] = fmaf(a[i], b[j], acc[i][j]);
        }
        __syncthreads();
    }

    // ---- deterministic cross-wave reduction: red = w0; += w1; += w2; += w3
    if (wv == 0) {
#pragma unroll
        for (int i = 0; i < 8; ++i)
#pragma unroll
            for (int j = 0; j < 8; ++j)
                red[i * 8 + lr][j * 8 + lc] = acc[i][j];
    }
    __syncthreads();
    for (int v = 1; v < NWAVE; ++v) {
        if (wv == v) {
#pragma unroll
            for (int i = 0; i < 8; ++i)
#pragma unroll
                for (int j = 0; j < 8; ++j)
                    red[i * 8 + lr][j * 8 + lc] += acc[i][j];
        }
        __syncthreads();
    }

    // ---- routing: one lane per token (threads 0..63)
    if (tid < MBLK) {
        const int t = tid;
        float s[NEXP];
        float m = -INFINITY;
#pragma unroll
        for (int e = 0; e < NEXP; ++e) { s[e] = red[t][e]; m = fmaxf(m, s[e]); }
        float sum = 0.f;
#pragma unroll
        for (int e = 0; e < NEXP; ++e) { s[e] = __expf(s[e] - m); sum += s[e]; }
        float inv = 1.f / sum;
#pragma unroll
        for (int e = 0; e < NEXP; ++e) s[e] *= inv;

        // group maxes (8 groups of 8)
        float gs[NGROUP];
#pragma unroll
        for (int g = 0; g < NGROUP; ++g) {
            float gm = s[g * 8];
#pragma unroll
            for (int q = 1; q < 8; ++q) gm = fmaxf(gm, s[g * 8 + q]);
            gs[g] = gm;
        }
        // top-3 groups, strict > => lowest index on ties (matches lax.top_k)
        unsigned gmask = 0;
        for (int r = 0; r < TOPKG; ++r) {
            int bg = 0; float bv = -INFINITY;
#pragma unroll
            for (int g = 0; g < NGROUP; ++g) {
                bool avail = !((gmask >> g) & 1);
                if (avail && gs[g] > bv) { bv = gs[g]; bg = g; }
            }
            gmask |= 1u << bg;
        }
        // top-6 experts over masked scores (masked -> 0.0, same as reference)
        unsigned long long chosen = 0ull;
        const int tok = row0 + t;
        for (int k = 0; k < TOPK; ++k) {
            int be = 0; float bv = -INFINITY;
#pragma unroll
            for (int e = 0; e < NEXP; ++e) {
                float v = ((gmask >> (e >> 3)) & 1u) ? s[e] : 0.f;
                bool avail = !((chosen >> e) & 1ull);
                if (avail && v > bv) { bv = v; be = e; }
            }
            chosen |= 1ull << be;
            out[(size_t)tok * TOPK + k] = (float)be;                       // idx as f32
            out[(size_t)half_out + (size_t)tok * TOPK + k] = bv;           // weight
        }
    }
}

extern "C" void kernel_launch(void* const* d_in, const int* in_sizes, int n_in,
                              void* d_out, int out_size, void* d_ws, size_t ws_size,
                              hipStream_t stream)
{
    const float* x = (const float*)d_in[0];
    const float* w = (const float*)d_in[1];
    float* out = (float*)d_out;
    const int half_out = out_size / 2;   // 98304 = 16384*6

    dim3 grid(TOKENS / MBLK);            // 256 blocks
    dim3 block(256);
    moe_gate_kernel<<<grid, block, 0, stream>>>(x, w, out, half_out);
}